// Round 24
// baseline (111.817 us; speedup 1.0000x reference)
//
#include <hip/hip_runtime.h>
#include <hip/hip_bf16.h>

#define Tlen 8192
#define Dd 256
#define NBc 128

typedef __attribute__((ext_vector_type(4))) float f32x4;
typedef __attribute__((ext_vector_type(8))) short bf16x8;

__device__ __forceinline__ unsigned short f2bf(float f){
  unsigned u = __builtin_bit_cast(unsigned, f);
  u += 0x7fffu + ((u >> 16) & 1u);
  return (unsigned short)(u >> 16);
}
__device__ __forceinline__ f32x4 mfma16(bf16x8 a, bf16x8 b, f32x4 c){
  return __builtin_amdgcn_mfma_f32_16x16x32_bf16(a, b, c, 0, 0, 0);
}
__device__ __forceinline__ void bar(){
  asm volatile("" ::: "memory");
  __builtin_amdgcn_s_barrier();
  asm volatile("" ::: "memory");
}
__device__ __forceinline__ bf16x8 pack8(f32x4 a0, f32x4 a1){
  bf16x8 o;
  o[0]=(short)f2bf(a0[0]); o[1]=(short)f2bf(a0[1]); o[2]=(short)f2bf(a0[2]); o[3]=(short)f2bf(a0[3]);
  o[4]=(short)f2bf(a1[0]); o[5]=(short)f2bf(a1[1]); o[6]=(short)f2bf(a1[2]); o[7]=(short)f2bf(a1[3]);
  return o;
}
#define GLL16(g, l) __builtin_amdgcn_global_load_lds( \
    (const __attribute__((address_space(1))) unsigned int*)(const void*)(g), \
    (__attribute__((address_space(3))) unsigned int*)(void*)(l), 16, 0, 0)

// DPP 16-lane row rotations (lane groups of 16 == DPP rows)
template<int C>
__device__ __forceinline__ int dppi(int x){
  return __builtin_amdgcn_update_dpp(x, x, C, 0xF, 0xF, false);
}
template<int C>
__device__ __forceinline__ float dppf(float x){
  return __builtin_bit_cast(float, dppi<C>(__builtin_bit_cast(int, x)));
}
__device__ __forceinline__ float dpp_sum16(float x){
  x += dppf<0x121>(x); x += dppf<0x122>(x); x += dppf<0x124>(x); x += dppf<0x128>(x);
  return x;
}

// Load A-fragment (row = lane&15) for 16x16x32: 8 consecutive k at (l>>4)*8
__device__ __forceinline__ bf16x8 load_qfrag(const float* qrow, int kc, int g){
  f32x4 v0 = *(const f32x4*)(qrow + kc*32 + g*8);
  f32x4 v1 = *(const f32x4*)(qrow + kc*32 + g*8 + 4);
  return pack8(v0, v1);
}

// ---------------- Prep: means (ck swizzled, cvt) + swizzled bf16 K blocks + swizzled bf16 V^T blocks
__global__ __launch_bounds__(256) void k_prep(const float* __restrict__ K, const float* __restrict__ V,
    unsigned short* __restrict__ ck, unsigned short* __restrict__ cvt,
    unsigned short* __restrict__ Vswz, unsigned short* __restrict__ Kswz, int do_k){
  __shared__ unsigned short Lt[64][72];
  int b = blockIdx.x >> 7, blk = blockIdx.x & 127;
  int t = threadIdx.x;
  const float* Kb = K + ((size_t)b*Tlen + (size_t)blk*64)*Dd;
  const float* Vb = V + ((size_t)b*Tlen + (size_t)blk*64)*Dd;
  {
    float sk=0.f, sv=0.f;
    #pragma unroll 8
    for (int i=0;i<64;i++){ sk += Kb[(size_t)i*Dd + t]; sv += Vb[(size_t)i*Dd + t]; }
    ck[((size_t)b*NBc + blk)*Dd + (((t>>3) ^ (blk&7))<<3) + (t&7)] = f2bf(sk*(1.f/64.f));
    cvt[((size_t)b*Dd + t)*NBc + blk] = f2bf(sv*(1.f/64.f));
  }
  if (do_k){
    unsigned short* kd = Kswz + ((size_t)(b*NBc + blk))*16384;
    #pragma unroll
    for (int i=0;i<8;i++){
      int id = i*256 + t, r = id>>5, c = id&31;
      f32x4 a0 = *(const f32x4*)(Kb + (size_t)r*Dd + c*8);
      f32x4 a1 = *(const f32x4*)(Kb + (size_t)r*Dd + c*8 + 4);
      *(bf16x8*)(kd + r*256 + ((c ^ (r&7))*8)) = pack8(a0,a1);
    }
  }
  unsigned short* vd = Vswz + ((size_t)(b*NBc + blk))*16384;
  for (int dt=0; dt<4; ++dt){
    __syncthreads();
    #pragma unroll
    for (int it=0; it<4; ++it){
      int idx = it*256 + t, r = idx>>4, c4 = idx&15;
      f32x4 v = *(const f32x4*)(Vb + (size_t)r*Dd + dt*64 + c4*4);
      #pragma unroll
      for (int ii=0;ii<4;ii++) Lt[c4*4+ii][r] = f2bf(v[ii]);
    }
    __syncthreads();
    int dd = t>>2, ch = t&3, d = dt*64 + dd;
    unsigned short tmp[16];
    #pragma unroll
    for (int u=0;u<16;u++) tmp[u] = Lt[dd][ch*16+u];
    *(bf16x8*)(vd + d*64 + (((ch*2  ) ^ (d&7))*8)) = *(bf16x8*)(tmp);
    *(bf16x8*)(vd + d*64 + (((ch*2+1) ^ (d&7))*8)) = *(bf16x8*)(tmp+8);
  }
}

// ---------------- swa phase: 64-q tile flash attention; result left SCALED in po (no out write)
template<bool KPRE>
__device__ __forceinline__ void swa_phase(char* RAW,
    const float* Q, const float* Kf,
    const unsigned short* Kswz, const unsigned short* Vswz,
    const float* gw, int b, int tile, f32x4* po){
  unsigned short* K0 = (unsigned short*)RAW;           // [2][16384] shorts (64 KB dbuf)
  unsigned short* Ps = (unsigned short*)(RAW + 65536); // [4096] shorts (8 KB): P [64 q][64 k] swizzled
  float* Lp = (float*)(RAW + 73728);                   // [2][64] floats

  int q0 = tile*64;
  int t = threadIdx.x, w = t>>6, l = t&63, g = l>>4, lr = l&15;
  int rg = w & 3;           // QK: q-group rg*16..+15
  int kh = w >> 2;          // QK: key-half kh*32..+31

  bf16x8 qa[8];
  const float* qrow = Q + ((size_t)b*Tlen + q0 + rg*16 + lr)*Dd;
  #pragma unroll
  for (int kc=0;kc<8;kc++) qa[kc] = load_qfrag(qrow, kc, g);

  __syncthreads();   // phase boundary
  asm volatile("s_waitcnt vmcnt(0)" ::: "memory");

  #pragma unroll
  for (int i=0;i<8;i++) po[i]=f32x4{0.f,0.f,0.f,0.f};
  float zs[4] = {0.f,0.f,0.f,0.f};

  int jb0 = tile - 8; if (jb0 < 0) jb0 = 0;
  const int jbmax = tile;
  const size_t bof = (size_t)b*NBc*16384;

  auto stage = [&](int buf, int jb){
    const unsigned short* ks = Kswz + bof + (size_t)jb*16384 + t*8;
    #pragma unroll
    for (int i=0;i<4;i++) GLL16(ks + i*4096, &K0[buf*16384 + t*8 + i*4096]);
  };
  int cur = 0;
  if constexpr (KPRE) stage(0, jb0);

  for (int jb = jb0; jb <= jbmax; ++jb){
    if constexpr (KPRE){
      // no leading barrier — prev iter's post-exp bar() ordered all waves past QK(jb-1)
      if (jb < jbmax){
        stage(cur^1, jb+1);
        asm volatile("s_waitcnt vmcnt(4)" ::: "memory");
      } else {
        asm volatile("s_waitcnt vmcnt(0)" ::: "memory");
      }
      bar();                                  // K0[cur] staged data visible to all waves
    } else {
      bar();
      {
        const float* kb = Kf + ((size_t)b*Tlen + (size_t)jb*64)*Dd;
        #pragma unroll
        for (int i=0;i<4;i++){
          int id = i*512 + t, r = id>>5, c = id&31;
          f32x4 a0 = *(const f32x4*)(kb + (size_t)r*Dd + c*8);
          f32x4 a1 = *(const f32x4*)(kb + (size_t)r*Dd + c*8 + 4);
          *(bf16x8*)(&K0[r*256 + ((c ^ (r&7))*8)]) = pack8(a0,a1);
        }
      }
      asm volatile("s_waitcnt vmcnt(0) lgkmcnt(0)" ::: "memory");
      bar();
    }

    // QK: S[16q x 32k] via 2 nf x 8 kc mfma16 (swizzled Ks LDS)
    f32x4 acc[2];
    acc[0]=f32x4{0.f,0.f,0.f,0.f}; acc[1]=f32x4{0.f,0.f,0.f,0.f};
    #pragma unroll
    for (int nf=0;nf<2;nf++){
      int key = kh*32 + nf*16 + lr;
      const unsigned short* rbase = &K0[cur*16384 + key*256];
      int xk = key & 7;
      #pragma unroll
      for (int kc=0;kc<8;kc++){
        bf16x8 kf = *(const bf16x8*)(rbase + (((kc*4+g) ^ xk)*8));
        acc[nf] = mfma16(qa[kc], kf, acc[nf]);
      }
    }
    // mask + exp + Ps write (swizzled) + zs accumulate
    #pragma unroll
    for (int nf=0;nf<2;nf++){
      int kloc = kh*32 + nf*16 + lr;
      int kglob = jb*64 + kloc;
      int kchunk = kloc >> 3;
      #pragma unroll
      for (int j=0;j<4;j++){
        int qloc = rg*16 + 4*g + j;
        int qg2 = q0 + qloc;
        float e = (kglob <= qg2 && kglob >= qg2-511) ? __expf(acc[nf][j]*0.0625f) : 0.f;
        zs[j] += e;
        Ps[qloc*64 + ((kchunk ^ (qloc&7))<<3) + (kloc&7)] = f2bf(e);
      }
    }
    asm volatile("s_waitcnt lgkmcnt(0)" ::: "memory");
    bar();                                    // P visible; also orders QK(jb) for next stage

    // PV: wave owns d-slice w*32..+31, all 64 q; V direct from pre-swizzled global
    {
      bf16x8 vf[2][2];
      #pragma unroll
      for (int nf2=0;nf2<2;nf2++){
        int d = w*32 + nf2*16 + lr;
        const unsigned short* vrow = Vswz + bof + (size_t)jb*16384 + (size_t)d*64;
        int xv = d & 7;
        #pragma unroll
        for (int k2=0;k2<2;k2++)
          vf[nf2][k2] = *(const bf16x8*)(vrow + (((k2*4+g) ^ xv)*8));
      }
      #pragma unroll
      for (int rg2=0;rg2<4;rg2++){
        int qloc = rg2*16 + lr;
        int xq = qloc & 7;
        bf16x8 pa0 = *(const bf16x8*)(&Ps[qloc*64 + (((0*4+g) ^ xq)<<3)]);
        bf16x8 pa1 = *(const bf16x8*)(&Ps[qloc*64 + (((1*4+g) ^ xq)<<3)]);
        #pragma unroll
        for (int nf2=0;nf2<2;nf2++){
          po[rg2*2+nf2] = mfma16(pa0, vf[nf2][0], po[rg2*2+nf2]);
          po[rg2*2+nf2] = mfma16(pa1, vf[nf2][1], po[rg2*2+nf2]);
        }
      }
    }
    if constexpr (KPRE) cur ^= 1;
  }

  // row sums: DPP over lr (keys), publish per key-half, combine; scale po IN REGISTERS
  #pragma unroll
  for (int j=0;j<4;j++) zs[j] = dpp_sum16(zs[j]);
  if (lr == 0){
    #pragma unroll
    for (int j=0;j<4;j++) Lp[kh*64 + rg*16 + 4*g + j] = zs[j];
  }
  __syncthreads();
  #pragma unroll
  for (int rg2=0;rg2<4;rg2++){
    #pragma unroll
    for (int j=0;j<4;j++){
      int qloc = rg2*16 + 4*g + j;
      float scl = gw[(size_t)b*Tlen + q0 + qloc] / (Lp[qloc] + Lp[64 + qloc]);
      #pragma unroll
      for (int nf2=0;nf2<2;nf2++) po[rg2*2+nf2][j] *= scl;
    }
  }
}

// ---------------- compsel phase: LDS-staged ck, DEDUPED QK (wave pair splits nf, exchanges via LDS),
// DPP extraction, PV wave-owns-d-slice accumulated into po; coalesced out write via LDS transpose
__device__ __forceinline__ void compsel_phase(char* RAW,
    const float* Q, const unsigned short* ck, const unsigned short* cvt,
    const float* gc, const float* gs, float* out, int b, int tile, f32x4* po){
  unsigned short* LB = (unsigned short*)RAW;   // ck tile (64 KB); later Pc, then fp32 out tile
  float* XC = (float*)(RAW + 65536);           // 16 KB score-exchange buffer

  int q0 = tile*64;
  int t = threadIdx.x, w = t >> 6, l = t & 63, g = l >> 4, lr = l & 15;
  int tr = w >> 1, half = w & 1;

  float gcv[2], gsv[2];
  #pragma unroll
  for (int jl=0;jl<2;jl++){
    int qq = q0 + tr*16 + 4*g + half*2 + jl;
    gcv[jl] = gc[(size_t)b*Tlen + qq];
    gsv[jl] = gs[(size_t)b*Tlen + qq];
  }
  bf16x8 qa[8];
  const float* qrow = Q + ((size_t)b*Tlen + q0 + tr*16 + lr)*Dd;
  #pragma unroll
  for (int kc=0;kc<8;kc++) qa[kc] = load_qfrag(qrow, kc, g);

  __syncthreads();   // phase boundary: swa done with K0/Ps region

  // stage full ck tile (64 KB, pre-swizzled) -> LDS once per block
  {
    const unsigned short* src = ck + (size_t)b*NBc*Dd;
    #pragma unroll
    for (int i=0;i<8;i++){
      int idx = i*512 + t;
      GLL16(src + idx*8, &LB[idx*8]);
    }
  }
  asm volatile("s_waitcnt vmcnt(0)" ::: "memory");
  bar();

  // QK: wave computes only its 4 local nf (half*4..+3) — partner computes the other 4
  f32x4 accp[4];
  #pragma unroll
  for (int nl=0;nl<4;nl++) accp[nl] = f32x4{0.f,0.f,0.f,0.f};
  #pragma unroll
  for (int nl=0;nl<4;nl++){
    int row = (half*4+nl)*16 + lr;
    const unsigned short* rbase = &LB[row*256];
    int xk = row & 7;
    #pragma unroll
    for (int kc=0;kc<8;kc++){
      bf16x8 bb = *(const bf16x8*)(rbase + (((kc*4+g) ^ xk)*8));
      accp[nl] = mfma16(qa[kc], bb, accp[nl]);
    }
  }
  #pragma unroll
  for (int nl=0;nl<4;nl++) accp[nl] *= 0.0625f;

  // exchange: give partner its j-pair of my 4 nf; 8 floats/lane each way
  #pragma unroll
  for (int nl=0;nl<4;nl++){
    #pragma unroll
    for (int jl=0;jl<2;jl++)
      XC[((size_t)w*64 + l)*8 + nl*2 + jl] = accp[nl][(1^half)*2 + jl];
  }
  asm volatile("s_waitcnt lgkmcnt(0)" ::: "memory");
  bar();   // exchange visible; also: all waves done reading ck LDS (LB reusable as Pc later)

  // full score set for my j-pair, all 8 nf (bit-identical to the duplicated computation)
  float sfull[8][2];
  {
    int pw = w ^ 1;
    #pragma unroll
    for (int nl=0;nl<4;nl++){
      #pragma unroll
      for (int jl=0;jl<2;jl++){
        sfull[half*4+nl][jl]     = accp[nl][half*2 + jl];
        sfull[(1^half)*4+nl][jl] = XC[((size_t)pw*64 + l)*8 + nl*2 + jl];
      }
    }
  }

  bool al[8];
  #pragma unroll
  for (int nf=0;nf<8;nf++) al[nf] = (nf*16+lr) <= tile;

  float e2[8][2];
  #pragma unroll
  for (int nf=0;nf<8;nf++){
    #pragma unroll
    for (int jl=0;jl<2;jl++) e2[nf][jl] = __expf(sfull[nf][jl]);
  }
  float rzc[2], rzs[2];
  {
    float zc2[2]={0.f,0.f}, zs2[2]={0.f,0.f};
    #pragma unroll
    for (int nf=0;nf<8;nf++){
      #pragma unroll
      for (int jl=0;jl<2;jl++){
        zc2[jl] += e2[nf][jl];
        zs2[jl] += al[nf] ? e2[nf][jl] : 0.f;
      }
    }
    #pragma unroll
    for (int jl=0;jl<2;jl++){
      rzc[jl] = 1.f / dpp_sum16(zc2[jl]);
      rzs[jl] = 1.f / dpp_sum16(zs2[jl]);
    }
  }

  float sm2[8][2];
  #pragma unroll
  for (int nf=0;nf<8;nf++){
    #pragma unroll
    for (int jl=0;jl<2;jl++) sm2[nf][jl] = al[nf] ? sfull[nf][jl] : -3e38f;
  }
  unsigned selm[2]={0,0};
  #pragma unroll 1
  for (int it=0; it<16; ++it){
    float bv[2]; int bi[2];
    #pragma unroll
    for (int jl=0;jl<2;jl++){
      float v = sm2[0][jl]; int n = lr;
      #pragma unroll
      for (int nf=1;nf<8;nf++){
        bool tk = sm2[nf][jl] > v;
        v = tk ? sm2[nf][jl] : v;
        n = tk ? nf*16+lr : n;
      }
      bv[jl]=v; bi[jl]=n;
    }
    #define DSTEP(CTRL) \
    _Pragma("unroll") \
    for (int jl=0;jl<2;jl++){ \
      float ov = dppf<CTRL>(bv[jl]); int oi = dppi<CTRL>(bi[jl]); \
      bool tk = (ov>bv[jl]) || (ov==bv[jl] && oi<bi[jl]); \
      bv[jl] = tk ? ov : bv[jl]; bi[jl] = tk ? oi : bi[jl]; \
    }
    DSTEP(0x121) DSTEP(0x122) DSTEP(0x124) DSTEP(0x128)
    #undef DSTEP
    #pragma unroll
    for (int jl=0;jl<2;jl++){
      selm[jl] |= (((bi[jl]&15)==lr) ? (1u<<(bi[jl]>>4)) : 0u);
      #pragma unroll
      for (int nf=0;nf<8;nf++)
        sm2[nf][jl] = (bi[jl] == nf*16+lr) ? -3e38f : sm2[nf][jl];
    }
  }

  unsigned short* Pc = LB;
  #pragma unroll
  for (int nf=0;nf<8;nf++){
    int n = nf*16+lr;
    #pragma unroll
    for (int jl=0;jl<2;jl++){
      float pcm = e2[nf][jl]*rzc[jl];
      float ps  = (al[nf] && ((selm[jl]>>nf)&1u)) ? e2[nf][jl]*rzs[jl] : 0.f;
      Pc[(tr*16 + 4*g + half*2 + jl)*136 + n] = f2bf(gcv[jl]*pcm + gsv[jl]*ps);
    }
  }
  __syncthreads();

  // PV: wave w owns d-slice w*32..+31 (cols nf2=2w,2w+1), all 64 q rows; accumulate into po
  const unsigned short* cvb = cvt + (size_t)b*Dd*NBc;
  bf16x8 vb[2][4];
  #pragma unroll
  for (int nf2=0;nf2<2;nf2++){
    int d = w*32 + nf2*16 + lr;
    #pragma unroll
    for (int kc=0;kc<4;kc++)
      vb[nf2][kc] = *(const bf16x8*)(cvb + (size_t)d*NBc + kc*32 + g*8);
  }
  #pragma unroll
  for (int rg2=0;rg2<4;rg2++){
    bf16x8 pa[4];
    #pragma unroll
    for (int kc=0;kc<4;kc++)
      pa[kc] = *(const bf16x8*)(&Pc[(rg2*16+lr)*136 + kc*32 + g*8]);
    #pragma unroll
    for (int nf2=0;nf2<2;nf2++){
      #pragma unroll
      for (int kc=0;kc<4;kc++)
        po[rg2*2+nf2] = mfma16(pa[kc], vb[nf2][kc], po[rg2*2+nf2]);
    }
  }

  // ---- coalesced out write via LDS transpose: OF[64][260] fp32 (66.5 KB in LB arena) ----
  __syncthreads();   // all Pc reads complete; LB reusable as fp32 out tile
  float* OF = (float*)LB;
  #pragma unroll
  for (int rg2=0;rg2<4;rg2++){
    #pragma unroll
    for (int nf2=0;nf2<2;nf2++){
      #pragma unroll
      for (int j=0;j<4;j++){
        OF[(rg2*16 + 4*g + j)*260 + w*32 + nf2*16 + lr] = po[rg2*2+nf2][j];
      }
    }
  }
  __syncthreads();
  // wave w stores rows w*8..w*8+7 as contiguous 128B runs (8 lanes x 16B per row)
  {
    int row = w*8 + (l>>3);
    float* orow = out + ((size_t)b*Tlen + q0 + row)*Dd;
    const float* frow = &OF[row*260];
    #pragma unroll
    for (int i=0;i<8;i++){
      int c4 = (l&7) + 8*i;
      *(f32x4*)(orow + c4*4) = *(const f32x4*)(frow + c4*4);
    }
  }
}

// ---------------- fused main kernel: swa (po in regs, scaled) -> compsel (accumulate + single write)
template<bool KPRE>
__global__ __launch_bounds__(512,4) void k_main(const float* __restrict__ Q, const float* __restrict__ Kf,
    const unsigned short* __restrict__ ck, const unsigned short* __restrict__ cvt,
    const unsigned short* __restrict__ Kswz, const unsigned short* __restrict__ Vswz,
    const float* __restrict__ gc, const float* __restrict__ gs, const float* __restrict__ gw,
    float* __restrict__ out, int nt){
  __shared__ __align__(16) char RAW[81920];   // 80 KB arena -> 2 blocks/CU
  int wg = blockIdx.x;
  int lin = ((nt & 7) == 0) ? ((wg & 7)*(nt >> 3) + (wg >> 3)) : wg;
  int b = lin >> 7, tile = lin & 127;
  f32x4 po[8];
  swa_phase<KPRE>(RAW, Q, Kf, Kswz, Vswz, gw, b, tile, po);
  compsel_phase(RAW, Q, ck, cvt, gc, gs, out, b, tile, po);
}

extern "C" void kernel_launch(void* const* d_in, const int* in_sizes, int n_in,
                              void* d_out, int out_size, void* d_ws, size_t ws_size,
                              hipStream_t stream) {
  const float* Q  = (const float*)d_in[0];
  const float* K  = (const float*)d_in[1];
  const float* V  = (const float*)d_in[2];
  const float* gc = (const float*)d_in[3];
  const float* gs = (const float*)d_in[4];
  const float* gwp= (const float*)d_in[5];
  float* out = (float*)d_out;
  int B = in_sizes[0] / (Tlen*Dd);

  unsigned short* ck  = (unsigned short*)d_ws;                    // [B][128][256] bf16, chunk-swizzled
  unsigned short* cvt = ck  + (size_t)B*NBc*Dd;                   // [B][256][128] bf16
  unsigned short* Vsw = cvt + (size_t)B*Dd*NBc;                   // [B][128 blk][256 d][64 k] bf16 swizzled
  unsigned short* Ksw = Vsw + (size_t)B*Tlen*Dd;                  // [B][128 blk][64 r][256 d] bf16 swizzled

  size_t need_full = ((size_t)B*((size_t)NBc*Dd + (size_t)Dd*NBc + 2*(size_t)Tlen*Dd))*2;
  bool kpre = ws_size >= need_full;
  int nt = B*128;

  k_prep<<<dim3(B*128), dim3(256), 0, stream>>>(K, V, ck, cvt, Vsw, Ksw, kpre?1:0);
  if (kpre) k_main<true ><<<dim3(nt), dim3(512), 0, stream>>>(Q, K, ck, cvt, Ksw, Vsw, gc, gs, gwp, out, nt);
  else      k_main<false><<<dim3(nt), dim3(512), 0, stream>>>(Q, K, ck, cvt, Ksw, Vsw, gc, gs, gwp, out, nt);
}

// Round 25
// 108.399 us; speedup vs baseline: 1.0315x; 1.0315x over previous
//
#include <hip/hip_runtime.h>
#include <hip/hip_bf16.h>

#define Tlen 8192
#define Dd 256
#define NBc 128

typedef __attribute__((ext_vector_type(4))) float f32x4;
typedef __attribute__((ext_vector_type(8))) short bf16x8;

__device__ __forceinline__ unsigned short f2bf(float f){
  unsigned u = __builtin_bit_cast(unsigned, f);
  u += 0x7fffu + ((u >> 16) & 1u);
  return (unsigned short)(u >> 16);
}
__device__ __forceinline__ f32x4 mfma16(bf16x8 a, bf16x8 b, f32x4 c){
  return __builtin_amdgcn_mfma_f32_16x16x32_bf16(a, b, c, 0, 0, 0);
}
__device__ __forceinline__ void bar(){
  asm volatile("" ::: "memory");
  __builtin_amdgcn_s_barrier();
  asm volatile("" ::: "memory");
}
__device__ __forceinline__ bf16x8 pack8(f32x4 a0, f32x4 a1){
  bf16x8 o;
  o[0]=(short)f2bf(a0[0]); o[1]=(short)f2bf(a0[1]); o[2]=(short)f2bf(a0[2]); o[3]=(short)f2bf(a0[3]);
  o[4]=(short)f2bf(a1[0]); o[5]=(short)f2bf(a1[1]); o[6]=(short)f2bf(a1[2]); o[7]=(short)f2bf(a1[3]);
  return o;
}
#define GLL16(g, l) __builtin_amdgcn_global_load_lds( \
    (const __attribute__((address_space(1))) unsigned int*)(const void*)(g), \
    (__attribute__((address_space(3))) unsigned int*)(void*)(l), 16, 0, 0)

// DPP 16-lane row rotations (lane groups of 16 == DPP rows)
template<int C>
__device__ __forceinline__ int dppi(int x){
  return __builtin_amdgcn_update_dpp(x, x, C, 0xF, 0xF, false);
}
template<int C>
__device__ __forceinline__ float dppf(float x){
  return __builtin_bit_cast(float, dppi<C>(__builtin_bit_cast(int, x)));
}
__device__ __forceinline__ float dpp_sum16(float x){
  x += dppf<0x121>(x); x += dppf<0x122>(x); x += dppf<0x124>(x); x += dppf<0x128>(x);
  return x;
}

// Load A-fragment (row = lane&15) for 16x16x32: 8 consecutive k at (l>>4)*8
__device__ __forceinline__ bf16x8 load_qfrag(const float* qrow, int kc, int g){
  f32x4 v0 = *(const f32x4*)(qrow + kc*32 + g*8);
  f32x4 v1 = *(const f32x4*)(qrow + kc*32 + g*8 + 4);
  return pack8(v0, v1);
}

// ---------------- Prep: means (ck swizzled, cvt) + swizzled bf16 K blocks + swizzled bf16 V^T blocks
__global__ __launch_bounds__(256) void k_prep(const float* __restrict__ K, const float* __restrict__ V,
    unsigned short* __restrict__ ck, unsigned short* __restrict__ cvt,
    unsigned short* __restrict__ Vswz, unsigned short* __restrict__ Kswz, int do_k){
  __shared__ unsigned short Lt[64][72];
  int b = blockIdx.x >> 7, blk = blockIdx.x & 127;
  int t = threadIdx.x;
  const float* Kb = K + ((size_t)b*Tlen + (size_t)blk*64)*Dd;
  const float* Vb = V + ((size_t)b*Tlen + (size_t)blk*64)*Dd;
  {
    float sk=0.f, sv=0.f;
    #pragma unroll 8
    for (int i=0;i<64;i++){ sk += Kb[(size_t)i*Dd + t]; sv += Vb[(size_t)i*Dd + t]; }
    ck[((size_t)b*NBc + blk)*Dd + (((t>>3) ^ (blk&7))<<3) + (t&7)] = f2bf(sk*(1.f/64.f));
    cvt[((size_t)b*Dd + t)*NBc + blk] = f2bf(sv*(1.f/64.f));
  }
  if (do_k){
    unsigned short* kd = Kswz + ((size_t)(b*NBc + blk))*16384;
    #pragma unroll
    for (int i=0;i<8;i++){
      int id = i*256 + t, r = id>>5, c = id&31;
      f32x4 a0 = *(const f32x4*)(Kb + (size_t)r*Dd + c*8);
      f32x4 a1 = *(const f32x4*)(Kb + (size_t)r*Dd + c*8 + 4);
      *(bf16x8*)(kd + r*256 + ((c ^ (r&7))*8)) = pack8(a0,a1);
    }
  }
  unsigned short* vd = Vswz + ((size_t)(b*NBc + blk))*16384;
  for (int dt=0; dt<4; ++dt){
    __syncthreads();
    #pragma unroll
    for (int it=0; it<4; ++it){
      int idx = it*256 + t, r = idx>>4, c4 = idx&15;
      f32x4 v = *(const f32x4*)(Vb + (size_t)r*Dd + dt*64 + c4*4);
      #pragma unroll
      for (int ii=0;ii<4;ii++) Lt[c4*4+ii][r] = f2bf(v[ii]);
    }
    __syncthreads();
    int dd = t>>2, ch = t&3, d = dt*64 + dd;
    unsigned short tmp[16];
    #pragma unroll
    for (int u=0;u<16;u++) tmp[u] = Lt[dd][ch*16+u];
    *(bf16x8*)(vd + d*64 + (((ch*2  ) ^ (d&7))*8)) = *(bf16x8*)(tmp);
    *(bf16x8*)(vd + d*64 + (((ch*2+1) ^ (d&7))*8)) = *(bf16x8*)(tmp+8);
  }
}

// ---------------- swa phase: 64-q tile flash attention; result left SCALED in po (no out write)
template<bool KPRE>
__device__ __forceinline__ void swa_phase(char* RAW,
    const float* Q, const float* Kf,
    const unsigned short* Kswz, const unsigned short* Vswz,
    const float* gw, int b, int tile, f32x4* po){
  unsigned short* K0 = (unsigned short*)RAW;           // [2][16384] shorts (64 KB dbuf)
  unsigned short* Ps = (unsigned short*)(RAW + 65536); // [4096] shorts (8 KB): P [64 q][64 k] swizzled
  float* Lp = (float*)(RAW + 73728);                   // [2][64] floats

  int q0 = tile*64;
  int t = threadIdx.x, w = t>>6, l = t&63, g = l>>4, lr = l&15;
  int rg = w & 3;           // QK: q-group rg*16..+15
  int kh = w >> 2;          // QK: key-half kh*32..+31

  bf16x8 qa[8];
  const float* qrow = Q + ((size_t)b*Tlen + q0 + rg*16 + lr)*Dd;
  #pragma unroll
  for (int kc=0;kc<8;kc++) qa[kc] = load_qfrag(qrow, kc, g);

  __syncthreads();   // phase boundary
  asm volatile("s_waitcnt vmcnt(0)" ::: "memory");

  #pragma unroll
  for (int i=0;i<8;i++) po[i]=f32x4{0.f,0.f,0.f,0.f};
  float zs[4] = {0.f,0.f,0.f,0.f};

  int jb0 = tile - 8; if (jb0 < 0) jb0 = 0;
  const int jbmax = tile;
  const size_t bof = (size_t)b*NBc*16384;

  auto stage = [&](int buf, int jb){
    const unsigned short* ks = Kswz + bof + (size_t)jb*16384 + t*8;
    #pragma unroll
    for (int i=0;i<4;i++) GLL16(ks + i*4096, &K0[buf*16384 + t*8 + i*4096]);
  };
  int cur = 0;
  if constexpr (KPRE) stage(0, jb0);

  for (int jb = jb0; jb <= jbmax; ++jb){
    if constexpr (KPRE){
      // no leading barrier — prev iter's post-exp bar() ordered all waves past QK(jb-1)
      if (jb < jbmax){
        stage(cur^1, jb+1);
        asm volatile("s_waitcnt vmcnt(4)" ::: "memory");
      } else {
        asm volatile("s_waitcnt vmcnt(0)" ::: "memory");
      }
      bar();                                  // K0[cur] staged data visible to all waves
    } else {
      bar();
      {
        const float* kb = Kf + ((size_t)b*Tlen + (size_t)jb*64)*Dd;
        #pragma unroll
        for (int i=0;i<4;i++){
          int id = i*512 + t, r = id>>5, c = id&31;
          f32x4 a0 = *(const f32x4*)(kb + (size_t)r*Dd + c*8);
          f32x4 a1 = *(const f32x4*)(kb + (size_t)r*Dd + c*8 + 4);
          *(bf16x8*)(&K0[r*256 + ((c ^ (r&7))*8)]) = pack8(a0,a1);
        }
      }
      asm volatile("s_waitcnt vmcnt(0) lgkmcnt(0)" ::: "memory");
      bar();
    }

    // QK: S[16q x 32k] via 2 nf x 8 kc mfma16 (swizzled Ks LDS)
    f32x4 acc[2];
    acc[0]=f32x4{0.f,0.f,0.f,0.f}; acc[1]=f32x4{0.f,0.f,0.f,0.f};
    #pragma unroll
    for (int nf=0;nf<2;nf++){
      int key = kh*32 + nf*16 + lr;
      const unsigned short* rbase = &K0[cur*16384 + key*256];
      int xk = key & 7;
      #pragma unroll
      for (int kc=0;kc<8;kc++){
        bf16x8 kf = *(const bf16x8*)(rbase + (((kc*4+g) ^ xk)*8));
        acc[nf] = mfma16(qa[kc], kf, acc[nf]);
      }
    }
    // mask + exp + Ps write (swizzled) + zs accumulate
    #pragma unroll
    for (int nf=0;nf<2;nf++){
      int kloc = kh*32 + nf*16 + lr;
      int kglob = jb*64 + kloc;
      int kchunk = kloc >> 3;
      #pragma unroll
      for (int j=0;j<4;j++){
        int qloc = rg*16 + 4*g + j;
        int qg2 = q0 + qloc;
        float e = (kglob <= qg2 && kglob >= qg2-511) ? __expf(acc[nf][j]*0.0625f) : 0.f;
        zs[j] += e;
        Ps[qloc*64 + ((kchunk ^ (qloc&7))<<3) + (kloc&7)] = f2bf(e);
      }
    }
    asm volatile("s_waitcnt lgkmcnt(0)" ::: "memory");
    bar();                                    // P visible; also orders QK(jb) for next stage

    // PV: wave owns d-slice w*32..+31, all 64 q; V direct from pre-swizzled global
    {
      bf16x8 vf[2][2];
      #pragma unroll
      for (int nf2=0;nf2<2;nf2++){
        int d = w*32 + nf2*16 + lr;
        const unsigned short* vrow = Vswz + bof + (size_t)jb*16384 + (size_t)d*64;
        int xv = d & 7;
        #pragma unroll
        for (int k2=0;k2<2;k2++)
          vf[nf2][k2] = *(const bf16x8*)(vrow + (((k2*4+g) ^ xv)*8));
      }
      #pragma unroll
      for (int rg2=0;rg2<4;rg2++){
        int qloc = rg2*16 + lr;
        int xq = qloc & 7;
        bf16x8 pa0 = *(const bf16x8*)(&Ps[qloc*64 + (((0*4+g) ^ xq)<<3)]);
        bf16x8 pa1 = *(const bf16x8*)(&Ps[qloc*64 + (((1*4+g) ^ xq)<<3)]);
        #pragma unroll
        for (int nf2=0;nf2<2;nf2++){
          po[rg2*2+nf2] = mfma16(pa0, vf[nf2][0], po[rg2*2+nf2]);
          po[rg2*2+nf2] = mfma16(pa1, vf[nf2][1], po[rg2*2+nf2]);
        }
      }
    }
    if constexpr (KPRE) cur ^= 1;
  }

  // row sums: DPP over lr (keys), publish per key-half, combine; scale po IN REGISTERS
  #pragma unroll
  for (int j=0;j<4;j++) zs[j] = dpp_sum16(zs[j]);
  if (lr == 0){
    #pragma unroll
    for (int j=0;j<4;j++) Lp[kh*64 + rg*16 + 4*g + j] = zs[j];
  }
  __syncthreads();
  #pragma unroll
  for (int rg2=0;rg2<4;rg2++){
    #pragma unroll
    for (int j=0;j<4;j++){
      int qloc = rg2*16 + 4*g + j;
      float scl = gw[(size_t)b*Tlen + q0 + qloc] / (Lp[qloc] + Lp[64 + qloc]);
      #pragma unroll
      for (int nf2=0;nf2<2;nf2++) po[rg2*2+nf2][j] *= scl;
    }
  }
}

// ---------------- compsel phase: full LDS-staged ck, QK from LDS, DPP extraction,
// PV wave-owns-d-slice w*32 ACCUMULATED into po; coalesced out write via LDS transpose
__device__ __forceinline__ void compsel_phase(unsigned short* LB,
    const float* Q, const unsigned short* ck, const unsigned short* cvt,
    const float* gc, const float* gs, float* out, int b, int tile, f32x4* po){
  int q0 = tile*64;
  int t = threadIdx.x, w = t >> 6, l = t & 63, g = l >> 4, lr = l & 15;
  int tr = w >> 1, half = w & 1;

  float gcv[2], gsv[2];
  #pragma unroll
  for (int jl=0;jl<2;jl++){
    int qq = q0 + tr*16 + 4*g + half*2 + jl;
    gcv[jl] = gc[(size_t)b*Tlen + qq];
    gsv[jl] = gs[(size_t)b*Tlen + qq];
  }
  bf16x8 qa[8];
  const float* qrow = Q + ((size_t)b*Tlen + q0 + tr*16 + lr)*Dd;
  #pragma unroll
  for (int kc=0;kc<8;kc++) qa[kc] = load_qfrag(qrow, kc, g);

  __syncthreads();   // phase boundary: swa done with K0/Ps region

  // stage full ck tile (64 KB, pre-swizzled) -> LDS once per block
  {
    const unsigned short* src = ck + (size_t)b*NBc*Dd;
    #pragma unroll
    for (int i=0;i<8;i++){
      int idx = i*512 + t;
      GLL16(src + idx*8, &LB[idx*8]);
    }
  }
  asm volatile("s_waitcnt vmcnt(0)" ::: "memory");
  bar();

  f32x4 acc[8];
  #pragma unroll
  for (int nf=0;nf<8;nf++) acc[nf] = f32x4{0.f,0.f,0.f,0.f};
  #pragma unroll
  for (int nf=0;nf<8;nf++){
    int row = nf*16+lr;
    const unsigned short* rbase = &LB[row*256];
    int xk = row & 7;
    #pragma unroll
    for (int kc=0;kc<8;kc++){
      bf16x8 bb = *(const bf16x8*)(rbase + (((kc*4+g) ^ xk)*8));
      acc[nf] = mfma16(qa[kc], bb, acc[nf]);
    }
  }
  #pragma unroll
  for (int nf=0;nf<8;nf++) acc[nf] *= 0.0625f;
  asm volatile("s_waitcnt lgkmcnt(0)" ::: "memory");
  bar();   // all waves done reading ck LDS; LB reusable as Pc below

  bool al[8];
  #pragma unroll
  for (int nf=0;nf<8;nf++) al[nf] = (nf*16+lr) <= tile;

  float e2[8][2];
  #pragma unroll
  for (int nf=0;nf<8;nf++){
    #pragma unroll
    for (int jl=0;jl<2;jl++) e2[nf][jl] = __expf(acc[nf][half*2+jl]);
  }
  float rzc[2], rzs[2];
  {
    float zc2[2]={0.f,0.f}, zs2[2]={0.f,0.f};
    #pragma unroll
    for (int nf=0;nf<8;nf++){
      #pragma unroll
      for (int jl=0;jl<2;jl++){
        zc2[jl] += e2[nf][jl];
        zs2[jl] += al[nf] ? e2[nf][jl] : 0.f;
      }
    }
    #pragma unroll
    for (int jl=0;jl<2;jl++){
      rzc[jl] = 1.f / dpp_sum16(zc2[jl]);
      rzs[jl] = 1.f / dpp_sum16(zs2[jl]);
    }
  }

  float sm2[8][2];
  #pragma unroll
  for (int nf=0;nf<8;nf++){
    #pragma unroll
    for (int jl=0;jl<2;jl++) sm2[nf][jl] = al[nf] ? acc[nf][half*2+jl] : -3e38f;
  }
  unsigned selm[2]={0,0};
  #pragma unroll 1
  for (int it=0; it<16; ++it){
    float bv[2]; int bi[2];
    #pragma unroll
    for (int jl=0;jl<2;jl++){
      float v = sm2[0][jl]; int n = lr;
      #pragma unroll
      for (int nf=1;nf<8;nf++){
        bool tk = sm2[nf][jl] > v;
        v = tk ? sm2[nf][jl] : v;
        n = tk ? nf*16+lr : n;
      }
      bv[jl]=v; bi[jl]=n;
    }
    #define DSTEP(CTRL) \
    _Pragma("unroll") \
    for (int jl=0;jl<2;jl++){ \
      float ov = dppf<CTRL>(bv[jl]); int oi = dppi<CTRL>(bi[jl]); \
      bool tk = (ov>bv[jl]) || (ov==bv[jl] && oi<bi[jl]); \
      bv[jl] = tk ? ov : bv[jl]; bi[jl] = tk ? oi : bi[jl]; \
    }
    DSTEP(0x121) DSTEP(0x122) DSTEP(0x124) DSTEP(0x128)
    #undef DSTEP
    #pragma unroll
    for (int jl=0;jl<2;jl++){
      selm[jl] |= (((bi[jl]&15)==lr) ? (1u<<(bi[jl]>>4)) : 0u);
      #pragma unroll
      for (int nf=0;nf<8;nf++)
        sm2[nf][jl] = (bi[jl] == nf*16+lr) ? -3e38f : sm2[nf][jl];
    }
  }

  unsigned short* Pc = LB;
  #pragma unroll
  for (int nf=0;nf<8;nf++){
    int n = nf*16+lr;
    #pragma unroll
    for (int jl=0;jl<2;jl++){
      float pcm = e2[nf][jl]*rzc[jl];
      float ps  = (al[nf] && ((selm[jl]>>nf)&1u)) ? e2[nf][jl]*rzs[jl] : 0.f;
      Pc[(tr*16 + 4*g + half*2 + jl)*136 + n] = f2bf(gcv[jl]*pcm + gsv[jl]*ps);
    }
  }
  __syncthreads();

  // PV: wave w owns d-slice w*32..+31 (cols nf2=2w,2w+1), all 64 q rows; accumulate into po
  const unsigned short* cvb = cvt + (size_t)b*Dd*NBc;
  bf16x8 vb[2][4];
  #pragma unroll
  for (int nf2=0;nf2<2;nf2++){
    int d = w*32 + nf2*16 + lr;
    #pragma unroll
    for (int kc=0;kc<4;kc++)
      vb[nf2][kc] = *(const bf16x8*)(cvb + (size_t)d*NBc + kc*32 + g*8);
  }
  #pragma unroll
  for (int rg2=0;rg2<4;rg2++){
    bf16x8 pa[4];
    #pragma unroll
    for (int kc=0;kc<4;kc++)
      pa[kc] = *(const bf16x8*)(&Pc[(rg2*16+lr)*136 + kc*32 + g*8]);
    #pragma unroll
    for (int nf2=0;nf2<2;nf2++){
      #pragma unroll
      for (int kc=0;kc<4;kc++)
        po[rg2*2+nf2] = mfma16(pa[kc], vb[nf2][kc], po[rg2*2+nf2]);
    }
  }

  // ---- coalesced out write via LDS transpose: OF[64][260] fp32 (66.5 KB in LB arena) ----
  __syncthreads();   // all Pc reads complete; LB reusable as fp32 out tile
  float* OF = (float*)LB;
  #pragma unroll
  for (int rg2=0;rg2<4;rg2++){
    #pragma unroll
    for (int nf2=0;nf2<2;nf2++){
      #pragma unroll
      for (int j=0;j<4;j++){
        OF[(rg2*16 + 4*g + j)*260 + w*32 + nf2*16 + lr] = po[rg2*2+nf2][j];
      }
    }
  }
  __syncthreads();
  // wave w stores rows w*8..w*8+7 as contiguous 128B runs (8 lanes x 16B per row)
  {
    int row = w*8 + (l>>3);
    float* orow = out + ((size_t)b*Tlen + q0 + row)*Dd;
    const float* frow = &OF[row*260];
    #pragma unroll
    for (int i=0;i<8;i++){
      int c4 = (l&7) + 8*i;
      *(f32x4*)(orow + c4*4) = *(const f32x4*)(frow + c4*4);
    }
  }
}

// ---------------- fused main kernel: swa (po in regs, scaled) -> compsel (accumulate + single write)
template<bool KPRE>
__global__ __launch_bounds__(512,4) void k_main(const float* __restrict__ Q, const float* __restrict__ Kf,
    const unsigned short* __restrict__ ck, const unsigned short* __restrict__ cvt,
    const unsigned short* __restrict__ Kswz, const unsigned short* __restrict__ Vswz,
    const float* __restrict__ gc, const float* __restrict__ gs, const float* __restrict__ gw,
    float* __restrict__ out, int nt){
  __shared__ __align__(16) char RAW[74240];   // 72.5 KB arena (Ks dbuf 64K + Ps 8K + Lp)
  int wg = blockIdx.x;
  int lin = ((nt & 7) == 0) ? ((wg & 7)*(nt >> 3) + (wg >> 3)) : wg;
  int b = lin >> 7, tile = lin & 127;
  f32x4 po[8];
  swa_phase<KPRE>(RAW, Q, Kf, Kswz, Vswz, gw, b, tile, po);
  compsel_phase((unsigned short*)RAW, Q, ck, cvt, gc, gs, out, b, tile, po);
}

extern "C" void kernel_launch(void* const* d_in, const int* in_sizes, int n_in,
                              void* d_out, int out_size, void* d_ws, size_t ws_size,
                              hipStream_t stream) {
  const float* Q  = (const float*)d_in[0];
  const float* K  = (const float*)d_in[1];
  const float* V  = (const float*)d_in[2];
  const float* gc = (const float*)d_in[3];
  const float* gs = (const float*)d_in[4];
  const float* gwp= (const float*)d_in[5];
  float* out = (float*)d_out;
  int B = in_sizes[0] / (Tlen*Dd);

  unsigned short* ck  = (unsigned short*)d_ws;                    // [B][128][256] bf16, chunk-swizzled
  unsigned short* cvt = ck  + (size_t)B*NBc*Dd;                   // [B][256][128] bf16
  unsigned short* Vsw = cvt + (size_t)B*Dd*NBc;                   // [B][128 blk][256 d][64 k] bf16 swizzled
  unsigned short* Ksw = Vsw + (size_t)B*Tlen*Dd;                  // [B][128 blk][64 r][256 d] bf16 swizzled

  size_t need_full = ((size_t)B*((size_t)NBc*Dd + (size_t)Dd*NBc + 2*(size_t)Tlen*Dd))*2;
  bool kpre = ws_size >= need_full;
  int nt = B*128;

  k_prep<<<dim3(B*128), dim3(256), 0, stream>>>(K, V, ck, cvt, Vsw, Ksw, kpre?1:0);
  if (kpre) k_main<true ><<<dim3(nt), dim3(512), 0, stream>>>(Q, K, ck, cvt, Ksw, Vsw, gc, gs, gwp, out, nt);
  else      k_main<false><<<dim3(nt), dim3(512), 0, stream>>>(Q, K, ck, cvt, Ksw, Vsw, gc, gs, gwp, out, nt);
}